// Round 1
// baseline (4785.250 us; speedup 1.0000x reference)
//
#include <hip/hip_runtime.h>
#include <hip/hip_bf16.h>

// GCN autoencoder: 4 layers sharing one COO adjacency (N=100000, E=3200000).
// Reassociation: spmm(adj, d1 @ W4) == (adj @ d1) @ W4  -> all spmms run at D<=32.

#define N_NODES 100000
#define N_EDGES 3200000

// ---------------------------------------------------------------------------
// mm1: h1[N,32] = x[N,512] @ W1[512,32]
// Thread = one row. x tile staged in LDS (coalesced), W1 rows are wave-uniform
// -> compiler scalarizes to s_load; 32 fp32 accumulators per lane.
// ---------------------------------------------------------------------------
__global__ __launch_bounds__(256) void mm1_kernel(
    const float* __restrict__ x, const float* __restrict__ W,
    float* __restrict__ out) {
  __shared__ float xt[256][68];  // pad 64->68: 16B-aligned rows, banks spread (17t+k)%32
  const int t = threadIdx.x;
  const int r0 = blockIdx.x * 256;

  float acc[32];
#pragma unroll
  for (int j = 0; j < 32; ++j) acc[j] = 0.f;

  for (int kc = 0; kc < 512; kc += 64) {
    __syncthreads();
    // stage 256 rows x 64 floats, coalesced float4
#pragma unroll
    for (int m = 0; m < 16; ++m) {
      int l = m * 1024 + t * 4;      // float index within 256x64 tile
      int rr = l >> 6, cc = l & 63;
      int gr = r0 + rr;
      float4 v = make_float4(0.f, 0.f, 0.f, 0.f);
      if (gr < N_NODES) v = *(const float4*)(x + (size_t)gr * 512 + kc + cc);
      *(float4*)&xt[rr][cc] = v;
    }
    __syncthreads();

    for (int k = 0; k < 64; k += 4) {
      float4 xv = *(const float4*)&xt[t][k];
#pragma unroll
      for (int u = 0; u < 4; ++u) {
        float xs = (u == 0) ? xv.x : (u == 1) ? xv.y : (u == 2) ? xv.z : xv.w;
        const float* wrow = W + (kc + k + u) * 32;  // wave-uniform -> s_load
#pragma unroll
        for (int j = 0; j < 32; ++j) acc[j] += xs * wrow[j];
      }
    }
  }

  const int r = r0 + t;
  if (r < N_NODES) {
#pragma unroll
    for (int j = 0; j < 32; j += 4) {
      *(float4*)(out + (size_t)r * 32 + j) =
          make_float4(acc[j], acc[j + 1], acc[j + 2], acc[j + 3]);
    }
  }
}

// ---------------------------------------------------------------------------
// spmm: out[r] += vals[e] * in[cols[e]]  (COO, atomics)
// Thread = (edge, float4 chunk): C=D/4 lanes gather one dense row coalesced.
// ---------------------------------------------------------------------------
template <int D>
__global__ __launch_bounds__(256) void spmm_kernel(
    const int* __restrict__ rows, const int* __restrict__ cols,
    const float* __restrict__ vals, const float* __restrict__ in,
    float* __restrict__ out) {
  constexpr int SH = (D == 32) ? 3 : 2;   // log2(D/4)
  constexpr int CM = (D / 4) - 1;
  int tid = blockIdx.x * 256 + threadIdx.x;
  int e = tid >> SH;
  int c = tid & CM;
  if (e >= N_EDGES) return;
  int r = rows[e];
  int cl = cols[e];
  float v = vals[e];
  float4 g = *(const float4*)(in + (size_t)cl * D + c * 4);
  float* o = out + (size_t)r * D + c * 4;
  __hip_atomic_fetch_add(o + 0, v * g.x, __ATOMIC_RELAXED, __HIP_MEMORY_SCOPE_AGENT);
  __hip_atomic_fetch_add(o + 1, v * g.y, __ATOMIC_RELAXED, __HIP_MEMORY_SCOPE_AGENT);
  __hip_atomic_fetch_add(o + 2, v * g.z, __ATOMIC_RELAXED, __HIP_MEMORY_SCOPE_AGENT);
  __hip_atomic_fetch_add(o + 3, v * g.w, __ATOMIC_RELAXED, __HIP_MEMORY_SCOPE_AGENT);
}

// ---------------------------------------------------------------------------
// mm_small: out[N,JD] = in[N,KD] @ W[KD,JD]   (thread = row, W via s_load)
// ---------------------------------------------------------------------------
template <int KD, int JD>
__global__ __launch_bounds__(256) void mm_small_kernel(
    const float* __restrict__ in, const float* __restrict__ W,
    float* __restrict__ out) {
  int r = blockIdx.x * 256 + threadIdx.x;
  if (r >= N_NODES) return;
  float xr[KD];
#pragma unroll
  for (int k = 0; k < KD; k += 4)
    *(float4*)&xr[k] = *(const float4*)(in + (size_t)r * KD + k);
  float acc[JD];
#pragma unroll
  for (int j = 0; j < JD; ++j) acc[j] = 0.f;
#pragma unroll
  for (int k = 0; k < KD; ++k) {
#pragma unroll
    for (int j = 0; j < JD; ++j) acc[j] += xr[k] * W[k * JD + j];  // W uniform
  }
#pragma unroll
  for (int j = 0; j < JD; j += 4)
    *(float4*)(out + (size_t)r * JD + j) = *(float4*)&acc[j];
}

// ---------------------------------------------------------------------------
// mm4: out[N,512] = s4[N,32] @ W4[32,512]
// Lane j owns W4[:,j] in 32 VGPRs; s4 row is wave-uniform -> s_load;
// store is perfectly coalesced (lane-consecutive floats).
// ---------------------------------------------------------------------------
__global__ __launch_bounds__(512) void mm4_kernel(
    const float* __restrict__ s4, const float* __restrict__ W,
    float* __restrict__ out, int rows_per_block) {
  const int j = threadIdx.x;  // 0..511
  float w[32];
#pragma unroll
  for (int k = 0; k < 32; ++k) w[k] = W[k * 512 + j];
  int r0 = blockIdx.x * rows_per_block;
  int r1 = r0 + rows_per_block;
  if (r1 > N_NODES) r1 = N_NODES;
  for (int r = r0; r < r1; ++r) {
    const float* srow = s4 + (size_t)r * 32;  // uniform -> scalar loads
    float a0 = 0.f, a1 = 0.f, a2 = 0.f, a3 = 0.f;
#pragma unroll
    for (int k = 0; k < 32; k += 4) {
      a0 += srow[k + 0] * w[k + 0];
      a1 += srow[k + 1] * w[k + 1];
      a2 += srow[k + 2] * w[k + 2];
      a3 += srow[k + 3] * w[k + 3];
    }
    out[(size_t)r * 512 + j] = (a0 + a1) + (a2 + a3);
  }
}

// ---------------------------------------------------------------------------
extern "C" void kernel_launch(void* const* d_in, const int* in_sizes, int n_in,
                              void* d_out, int out_size, void* d_ws, size_t ws_size,
                              hipStream_t stream) {
  const float* x     = (const float*)d_in[0];
  const int*   arows = (const int*)d_in[1];
  const int*   acols = (const int*)d_in[2];
  const float* avals = (const float*)d_in[3];
  const float* W1    = (const float*)d_in[4];  // [512,32]
  const float* W2    = (const float*)d_in[5];  // [32,16]
  const float* W3    = (const float*)d_in[6];  // [16,32]
  const float* W4    = (const float*)d_in[7];  // [32,512]

  float* out = (float*)d_out;
  float* dec = out;                            // [N,512]
  float* enc = out + (size_t)N_NODES * 512;    // [N,16]

  float* A = (float*)d_ws;                     // [N,32] scratch
  float* B = A + (size_t)N_NODES * 32;         // [N,32] scratch

  const int mmGrid   = (N_NODES + 255) / 256;
  const int sp32Grid = (int)(((long)N_EDGES * 8 + 255) / 256);
  const int sp16Grid = (int)(((long)N_EDGES * 4 + 255) / 256);

  // h1 = x @ W1 -> A
  mm1_kernel<<<mmGrid, 256, 0, stream>>>(x, W1, A);

  // e1 = adj @ h1 -> B
  hipMemsetAsync(B, 0, (size_t)N_NODES * 32 * sizeof(float), stream);
  spmm_kernel<32><<<sp32Grid, 256, 0, stream>>>(arows, acols, avals, A, B);

  // h2 = e1 @ W2 -> A (uses first N*16 of A)
  mm_small_kernel<32, 16><<<mmGrid, 256, 0, stream>>>(B, W2, A);

  // e2 = adj @ h2 -> enc (in d_out)
  hipMemsetAsync(enc, 0, (size_t)N_NODES * 16 * sizeof(float), stream);
  spmm_kernel<16><<<sp16Grid, 256, 0, stream>>>(arows, acols, avals, A, enc);

  // h3 = e2 @ W3 -> B
  mm_small_kernel<16, 32><<<mmGrid, 256, 0, stream>>>(enc, W3, B);

  // d1 = adj @ h3 -> A
  hipMemsetAsync(A, 0, (size_t)N_NODES * 32 * sizeof(float), stream);
  spmm_kernel<32><<<sp32Grid, 256, 0, stream>>>(arows, acols, avals, B, A);

  // s4 = adj @ d1 -> B
  hipMemsetAsync(B, 0, (size_t)N_NODES * 32 * sizeof(float), stream);
  spmm_kernel<32><<<sp32Grid, 256, 0, stream>>>(arows, acols, avals, A, B);

  // decoded2 = s4 @ W4 -> dec
  mm4_kernel<<<(N_NODES + 63) / 64, 512, 0, stream>>>(B, W4, dec, 64);
}

// Round 2
// 826.779 us; speedup vs baseline: 5.7878x; 5.7878x over previous
//
#include <hip/hip_runtime.h>
#include <hip/hip_bf16.h>

// GCN autoencoder: 4 layers sharing one COO adjacency (N=100000, E=3200000).
// Reassociation: spmm(adj, d1 @ W4) == (adj @ d1) @ W4  -> all spmms run at D<=32.
// Round 2: atomics killed the SpMM (1.6 GB HBM atomic write-through per layer).
// Build CSR once (counting sort) in d_out's decoded2 region, then 4x atomic-free
// row-parallel SpMMs.

#define N_NODES 100000
#define N_EDGES 3200000
#define SCAN_BLOCKS ((N_NODES + 1023) / 1024)  // 98

// ---------------------------------------------------------------------------
// mm1: h1[N,32] = x[N,512] @ W1[512,32]
// ---------------------------------------------------------------------------
__global__ __launch_bounds__(256) void mm1_kernel(
    const float* __restrict__ x, const float* __restrict__ W,
    float* __restrict__ out) {
  __shared__ float xt[256][68];
  const int t = threadIdx.x;
  const int r0 = blockIdx.x * 256;

  float acc[32];
#pragma unroll
  for (int j = 0; j < 32; ++j) acc[j] = 0.f;

  for (int kc = 0; kc < 512; kc += 64) {
    __syncthreads();
#pragma unroll
    for (int m = 0; m < 16; ++m) {
      int l = m * 1024 + t * 4;
      int rr = l >> 6, cc = l & 63;
      int gr = r0 + rr;
      float4 v = make_float4(0.f, 0.f, 0.f, 0.f);
      if (gr < N_NODES) v = *(const float4*)(x + (size_t)gr * 512 + kc + cc);
      *(float4*)&xt[rr][cc] = v;
    }
    __syncthreads();

    for (int k = 0; k < 64; k += 4) {
      float4 xv = *(const float4*)&xt[t][k];
#pragma unroll
      for (int u = 0; u < 4; ++u) {
        float xs = (u == 0) ? xv.x : (u == 1) ? xv.y : (u == 2) ? xv.z : xv.w;
        const float* wrow = W + (kc + k + u) * 32;  // wave-uniform -> s_load
#pragma unroll
        for (int j = 0; j < 32; ++j) acc[j] += xs * wrow[j];
      }
    }
  }

  const int r = r0 + t;
  if (r < N_NODES) {
#pragma unroll
    for (int j = 0; j < 32; j += 4)
      *(float4*)(out + (size_t)r * 32 + j) =
          make_float4(acc[j], acc[j + 1], acc[j + 2], acc[j + 3]);
  }
}

// ---------------------------------------------------------------------------
// CSR build: histogram -> 2-level exclusive scan -> scatter (counting sort)
// ---------------------------------------------------------------------------
__global__ __launch_bounds__(256) void hist_kernel(
    const int* __restrict__ rows, int* __restrict__ cnt) {
  int e = blockIdx.x * 256 + threadIdx.x;
  if (e < N_EDGES) atomicAdd(&cnt[rows[e]], 1);
}

__global__ __launch_bounds__(256) void scan1_kernel(
    const int* __restrict__ cnt, int* __restrict__ outp,
    int* __restrict__ blk, int n) {
  __shared__ int sdata[256];
  int b = blockIdx.x;
  int base = b * 1024;
  int t = threadIdx.x;
  int v[4];
  int s = 0;
#pragma unroll
  for (int u = 0; u < 4; ++u) {
    int i = base + t * 4 + u;
    v[u] = (i < n) ? cnt[i] : 0;
    s += v[u];
  }
  sdata[t] = s;
  __syncthreads();
  for (int off = 1; off < 256; off <<= 1) {
    int x = (t >= off) ? sdata[t - off] : 0;
    __syncthreads();
    sdata[t] += x;
    __syncthreads();
  }
  int excl = (t == 0) ? 0 : sdata[t - 1];
  if (t == 255) blk[b] = sdata[255];
  int run = excl;
#pragma unroll
  for (int u = 0; u < 4; ++u) {
    int i = base + t * 4 + u;
    if (i < n) outp[i] = run;
    run += v[u];
  }
}

__global__ void scan2_kernel(int* __restrict__ blk, int nblk) {
  if (threadIdx.x == 0) {
    int run = 0;
    for (int i = 0; i < nblk; ++i) { int v = blk[i]; blk[i] = run; run += v; }
  }
}

__global__ __launch_bounds__(256) void scan3_kernel(
    int* __restrict__ rp, int* __restrict__ cur,
    const int* __restrict__ blk, int n, int total) {
  int b = blockIdx.x, t = threadIdx.x;
  int add = blk[b];
  int base = b * 1024 + t * 4;
#pragma unroll
  for (int u = 0; u < 4; ++u) {
    int i = base + u;
    if (i < n) { int v = rp[i] + add; rp[i] = v; cur[i] = v; }
  }
  if (b == 0 && t == 0) rp[n] = total;
}

__global__ __launch_bounds__(256) void scatter_kernel(
    const int* __restrict__ rows, const int* __restrict__ cols,
    const float* __restrict__ vals, int* __restrict__ cursor,
    int2* __restrict__ colval) {
  int e = blockIdx.x * 256 + threadIdx.x;
  if (e >= N_EDGES) return;
  int r = rows[e];
  int pos = atomicAdd(&cursor[r], 1);
  colval[pos] = make_int2(cols[e], __float_as_int(vals[e]));
}

// ---------------------------------------------------------------------------
// CSR SpMM: out[r,:] = sum_k val_k * in[col_k,:].  D/4 lanes per row, float4
// gathers (128B per edge across lanes), register accumulate, one coalesced
// non-atomic write. Writes ALL rows (zero rows included -> no memset needed).
// ---------------------------------------------------------------------------
template <int D>
__global__ __launch_bounds__(256) void spmm_csr_kernel(
    const int* __restrict__ rp, const int2* __restrict__ colval,
    const float* __restrict__ in, float* __restrict__ out) {
  constexpr int L = D / 4;            // lanes per row
  constexpr int RPB = 256 / L;        // rows per block
  int t = threadIdx.x;
  int r = blockIdx.x * RPB + t / L;
  int c = (t % L) * 4;
  if (r >= N_NODES) return;
  int k0 = rp[r], k1 = rp[r + 1];
  float4 acc = make_float4(0.f, 0.f, 0.f, 0.f);
  int k = k0;
  for (; k + 1 < k1; k += 2) {        // 2-way unroll: two gathers in flight
    int2 cv0 = colval[k];
    int2 cv1 = colval[k + 1];
    float4 g0 = *(const float4*)(in + (size_t)cv0.x * D + c);
    float4 g1 = *(const float4*)(in + (size_t)cv1.x * D + c);
    float v0 = __int_as_float(cv0.y), v1 = __int_as_float(cv1.y);
    acc.x += v0 * g0.x; acc.y += v0 * g0.y; acc.z += v0 * g0.z; acc.w += v0 * g0.w;
    acc.x += v1 * g1.x; acc.y += v1 * g1.y; acc.z += v1 * g1.z; acc.w += v1 * g1.w;
  }
  if (k < k1) {
    int2 cv = colval[k];
    float v = __int_as_float(cv.y);
    float4 g = *(const float4*)(in + (size_t)cv.x * D + c);
    acc.x += v * g.x; acc.y += v * g.y; acc.z += v * g.z; acc.w += v * g.w;
  }
  *(float4*)(out + (size_t)r * D + c) = acc;
}

// ---------------------------------------------------------------------------
// mm_small: out[N,JD] = in[N,KD] @ W[KD,JD]
// ---------------------------------------------------------------------------
template <int KD, int JD>
__global__ __launch_bounds__(256) void mm_small_kernel(
    const float* __restrict__ in, const float* __restrict__ W,
    float* __restrict__ out) {
  int r = blockIdx.x * 256 + threadIdx.x;
  if (r >= N_NODES) return;
  float xr[KD];
#pragma unroll
  for (int k = 0; k < KD; k += 4)
    *(float4*)&xr[k] = *(const float4*)(in + (size_t)r * KD + k);
  float acc[JD];
#pragma unroll
  for (int j = 0; j < JD; ++j) acc[j] = 0.f;
#pragma unroll
  for (int k = 0; k < KD; ++k) {
#pragma unroll
    for (int j = 0; j < JD; ++j) acc[j] += xr[k] * W[k * JD + j];
  }
#pragma unroll
  for (int j = 0; j < JD; j += 4)
    *(float4*)(out + (size_t)r * JD + j) = *(float4*)&acc[j];
}

// ---------------------------------------------------------------------------
// mm4: out[N,512] = s4[N,32] @ W4[32,512]
// ---------------------------------------------------------------------------
__global__ __launch_bounds__(512) void mm4_kernel(
    const float* __restrict__ s4, const float* __restrict__ W,
    float* __restrict__ out, int rows_per_block) {
  const int j = threadIdx.x;
  float w[32];
#pragma unroll
  for (int k = 0; k < 32; ++k) w[k] = W[k * 512 + j];
  int r0 = blockIdx.x * rows_per_block;
  int r1 = r0 + rows_per_block;
  if (r1 > N_NODES) r1 = N_NODES;
  for (int r = r0; r < r1; ++r) {
    const float* srow = s4 + (size_t)r * 32;  // uniform -> scalar loads
    float a0 = 0.f, a1 = 0.f, a2 = 0.f, a3 = 0.f;
#pragma unroll
    for (int k = 0; k < 32; k += 4) {
      a0 += srow[k + 0] * w[k + 0];
      a1 += srow[k + 1] * w[k + 1];
      a2 += srow[k + 2] * w[k + 2];
      a3 += srow[k + 3] * w[k + 3];
    }
    out[(size_t)r * 512 + j] = (a0 + a1) + (a2 + a3);
  }
}

// ---------------------------------------------------------------------------
extern "C" void kernel_launch(void* const* d_in, const int* in_sizes, int n_in,
                              void* d_out, int out_size, void* d_ws, size_t ws_size,
                              hipStream_t stream) {
  const float* x     = (const float*)d_in[0];
  const int*   arows = (const int*)d_in[1];
  const int*   acols = (const int*)d_in[2];
  const float* avals = (const float*)d_in[3];
  const float* W1    = (const float*)d_in[4];  // [512,32]
  const float* W2    = (const float*)d_in[5];  // [32,16]
  const float* W3    = (const float*)d_in[6];  // [16,32]
  const float* W4    = (const float*)d_in[7];  // [32,512]

  float* out = (float*)d_out;
  float* dec = out;                            // [N,512] written LAST (mm4)
  float* enc = out + (size_t)N_NODES * 512;    // [N,16]

  // Ping-pong buffers in d_ws (25.6 MB, proven available in round 1).
  float* A = (float*)d_ws;                     // [N,32]
  float* B = A + (size_t)N_NODES * 32;         // [N,32]

  // CSR scratch lives in the decoded2 region of d_out: it is only written by
  // the FINAL kernel (mm4), which fully overwrites it. 26.4 MB << 204.8 MB.
  int2* colval  = (int2*)dec;                  // [E] (col, val-bits)
  int*  row_ptr = (int*)(colval + N_EDGES);    // [N+1]
  int*  cursor  = row_ptr + N_NODES + 1;       // [N]
  int*  blk     = cursor + N_NODES;            // [SCAN_BLOCKS]

  const int mmGrid   = (N_NODES + 255) / 256;
  const int edgeGrid = (N_EDGES + 255) / 256;

  // ---- build CSR (once; reused by all 4 SpMMs) ----
  hipMemsetAsync(cursor, 0, (size_t)N_NODES * sizeof(int), stream);
  hist_kernel<<<edgeGrid, 256, 0, stream>>>(arows, cursor);
  scan1_kernel<<<SCAN_BLOCKS, 256, 0, stream>>>(cursor, row_ptr, blk, N_NODES);
  scan2_kernel<<<1, 64, 0, stream>>>(blk, SCAN_BLOCKS);
  scan3_kernel<<<SCAN_BLOCKS, 256, 0, stream>>>(row_ptr, cursor, blk, N_NODES, N_EDGES);
  scatter_kernel<<<edgeGrid, 256, 0, stream>>>(arows, acols, avals, cursor, colval);

  // ---- pipeline ----
  mm1_kernel<<<mmGrid, 256, 0, stream>>>(x, W1, A);                       // h1 -> A
  spmm_csr_kernel<32><<<(N_NODES + 31) / 32, 256, 0, stream>>>(row_ptr, colval, A, B);   // e1 -> B
  mm_small_kernel<32, 16><<<mmGrid, 256, 0, stream>>>(B, W2, A);          // h2 -> A
  spmm_csr_kernel<16><<<(N_NODES + 63) / 64, 256, 0, stream>>>(row_ptr, colval, A, enc); // e2 -> enc
  mm_small_kernel<16, 32><<<mmGrid, 256, 0, stream>>>(enc, W3, B);        // h3 -> B
  spmm_csr_kernel<32><<<(N_NODES + 31) / 32, 256, 0, stream>>>(row_ptr, colval, B, A);   // d1 -> A
  spmm_csr_kernel<32><<<(N_NODES + 31) / 32, 256, 0, stream>>>(row_ptr, colval, A, B);   // s4 -> B
  mm4_kernel<<<(N_NODES + 63) / 64, 512, 0, stream>>>(B, W4, dec, 64);    // dec
}